// Round 8
// baseline (45.321 us; speedup 1.0000x reference)
//
#include <hip/hip_runtime.h>

// LocalAveragePoolingSegmenter — gran-2 fp16 local partials + fp16 chunk sums
// + fp32 chunk scan (widened) + XCD-affine token kernel with NT output stores.
// B=16, T_AUDIO=4096, T_TEXT=1024, D=512.
// Output = concat( segmented_feats [B,Tt,D] f32 , text_token_len [B] as f32 ).
//
// P[b][c][j][d4] (j=0..6, fp16): local inclusive sum of frames [16c, 16c+2(j+1)).
// S [b][c][d4]   (fp16)        : chunk sums (16 frames).
// C [b][c][d4]   (c=0..256, f32): global exclusive prefix at chunk granularity.
// E[x] = C[x>>4] + (k2? P[..][k2-1] : 0) + (x&1 ? audio[x-1] : 0),  k2=(x&15)>>1.

constexpr int Bv  = 16;
constexpr int TA  = 4096;
constexpr int TT  = 1024;
constexpr int Dv  = 512;
constexpr int D4  = Dv / 4;     // 128 float4 per row
constexpr int CH  = 16;         // frames per chunk
constexpr int NCk = TA / CH;    // 256 chunks per b
constexpr int NC1 = NCk + 1;
constexpr int NSL = 7;          // gran-2 partial slots per chunk

typedef float    f32x4 __attribute__((ext_vector_type(4)));
typedef _Float16 f16x4 __attribute__((ext_vector_type(4)));

__device__ __forceinline__ void f4add(float4& a, const float4& v) {
    a.x += v.x; a.y += v.y; a.z += v.z; a.w += v.w;
}
__device__ __forceinline__ void f4addh(float4& a, const f16x4& v) {
    a.x += (float)v.x; a.y += (float)v.y; a.z += (float)v.z; a.w += (float)v.w;
}
__device__ __forceinline__ f16x4 toh4(const float4& v) {
    f16x4 r = { (_Float16)v.x, (_Float16)v.y, (_Float16)v.z, (_Float16)v.w };
    return r;
}

// K1: per (b, chunk, d4): fp16 gran-2 partials (7 slots) -> P, fp16 chunk sum -> S.
// (round-5 structure: compiler's own interleave is at the BW floor)
__global__ __launch_bounds__(256) void k_partials(
    const float4* __restrict__ A, f16x4* __restrict__ P, f16x4* __restrict__ S)
{
    int g  = blockIdx.x * 256 + threadIdx.x;   // [0, Bv*NCk*D4)
    int d4 = g & (D4 - 1);
    int c  = (g >> 7) & (NCk - 1);
    int b  = g >> 15;
    size_t abase = (size_t)(b * TA + c * CH) * D4 + d4;
    size_t pbase = ((size_t)(b * NCk + c) * NSL) * D4 + d4;
    float4 acc = {0.f, 0.f, 0.f, 0.f};
    #pragma unroll
    for (int i = 0; i < CH; ++i) {
        float4 v = A[abase + (size_t)i * D4];
        f4add(acc, v);
        if ((i & 1) && i < 15)                 // i = 1,3,...,13 -> slot (i-1)/2
            P[pbase + (size_t)((i - 1) >> 1) * D4] = toh4(acc);
    }
    S[(size_t)(b * NCk + c) * D4 + d4] = toh4(acc);
}

// K2: chunk-level exclusive scan S(fp16) -> C(fp32), widened: 512 one-wave
// blocks (2/CU), 4 columns per block, 16 threads x 16 chunks per column.
__global__ __launch_bounds__(64) void k_scan(
    const f16x4* __restrict__ S, float4* __restrict__ C,
    const int* __restrict__ tlen, float* __restrict__ outt)
{
    __shared__ float4 lds[16][4];
    int tid = threadIdx.x;
    int col = tid & 3;
    int g   = tid >> 2;                    // 0..15
    int b   = blockIdx.x >> 5;             // 32 blocks per b
    int d4  = (blockIdx.x & 31) * 4 + col;

    float4 run = {0.f, 0.f, 0.f, 0.f};
    float4 excl[16];
    #pragma unroll
    for (int i = 0; i < 16; ++i) {
        excl[i] = run;
        f4addh(run, S[(size_t)(b * NCk + g * 16 + i) * D4 + d4]);
    }
    lds[g][col] = run;                     // group total
    __syncthreads();
    float4 go = {0.f, 0.f, 0.f, 0.f};      // exclusive offset over groups
    for (int gp = 0; gp < g; ++gp)
        f4add(go, lds[gp][col]);

    size_t cb = (size_t)b * NC1 * D4 + d4;
    #pragma unroll
    for (int i = 0; i < 16; ++i) {
        float4 cex = go;
        f4add(cex, excl[i]);
        C[cb + (size_t)(g * 16 + i) * D4] = cex;
    }
    if (g == 15) {
        float4 tot = go;
        f4add(tot, run);
        C[cb + (size_t)NCk * D4] = tot;    // C[b][256] = grand total
    }
    if (blockIdx.x == 0 && tid < Bv)
        outt[tid] = (float)tlen[tid];
}

// K3: per-token mean (round-5 optimum: 128 threads/token, NT output stores).
// XCD-affine: batch b pinned to XCD b&7 (C/P L2-resident).
__global__ __launch_bounds__(128) void k_tokens(
    const float4* __restrict__ A, const f16x4* __restrict__ P,
    const float4* __restrict__ C, const int* __restrict__ tlen,
    const int* __restrict__ align, float4* __restrict__ out)
{
    int xcd  = blockIdx.x & 7;
    int slot = blockIdx.x >> 3;            // [0, 2048)
    int b  = xcd + 8 * (slot >> 10);       // batches {xcd, xcd+8}
    int t  = slot & (TT - 1);
    int bt = b * TT + t;
    int d4 = threadIdx.x;
    size_t ob = (size_t)bt * D4 + d4;

    if (t >= tlen[b]) {
        f32x4 z = {0.f, 0.f, 0.f, 0.f};
        __builtin_nontemporal_store(z, (f32x4*)&out[ob]);
        return;
    }
    int s = align[2 * bt];
    int e = align[2 * bt + 1];             // 0 <= s <= e <= TA-1

    const float4* Ab = A + (size_t)b * TA * D4;
    const float4* Cb = C + (size_t)b * NC1 * D4;
    const f16x4*  Pb = P + (size_t)b * NCk * NSL * D4;

    auto Eval = [&](int x) -> float4 {     // sum of frames < x, x in [0, TA]
        int c  = x >> 4;
        int k2 = (x & 15) >> 1;
        float4 v = Cb[(size_t)c * D4 + d4];
        if (k2) f4addh(v, Pb[((size_t)c * NSL + (k2 - 1)) * D4 + d4]);
        if (x & 1) f4add(v, Ab[(size_t)(x - 1) * D4 + d4]);
        return v;
    };

    float4 hi = Eval(e + 1);
    float4 lo = Eval(s);
    float inv = 1.f / (float)(e - s + 1);
    f32x4 r = { (hi.x - lo.x) * inv, (hi.y - lo.y) * inv,
                (hi.z - lo.z) * inv, (hi.w - lo.w) * inv };
    __builtin_nontemporal_store(r, (f32x4*)&out[ob]);
}

extern "C" void kernel_launch(void* const* d_in, const int* in_sizes, int n_in,
                              void* d_out, int out_size, void* d_ws, size_t ws_size,
                              hipStream_t stream)
{
    const float* audio = (const float*)d_in[0];        // [B,TA,D] f32
    const int*   tlen  = (const int*)d_in[4];          // [B] i32
    const int*   align = (const int*)d_in[5];          // [B,TT,2] i32
    float* out = (float*)d_out;

    // ws layout: P fp16 [Bv*NCk*NSL*D4], S fp16 [Bv*NCk*D4], C fp32 [Bv*NC1*D4]
    f16x4*  P = (f16x4*)d_ws;
    f16x4*  S = P + (size_t)Bv * NCk * NSL * D4;
    float4* C = (float4*)(S + (size_t)Bv * NCk * D4);

    k_partials<<<(Bv * NCk * D4) / 256, 256, 0, stream>>>(
        (const float4*)audio, P, S);
    k_scan<<<Bv * 32, 64, 0, stream>>>(
        S, C, tlen, out + (size_t)Bv * TT * Dv);
    k_tokens<<<Bv * TT, 128, 0, stream>>>(
        (const float4*)audio, P, C, tlen, align, (float4*)out);
}